// Round 5
// 75.545 us; speedup vs baseline: 1.0288x; 1.0288x over previous
//
#include <hip/hip_runtime.h>
#include <stdint.h>

#define S_LEN 2048
#define NH    8
#define TQ    32            // queries per block
#define PVT   168           // Vt LDS stride (bf16): 336 B rows, b128-aligned
#define PP    168           // P  LDS stride (bf16), same property

typedef __attribute__((ext_vector_type(8))) short  short8;   // 8 bf16 (4 VGPRs)
typedef __attribute__((ext_vector_type(4))) float  floatx4;  // MFMA C/D
typedef __attribute__((ext_vector_type(2))) unsigned int uint32x2;

__device__ __forceinline__ uint16_t f2b(float f) {           // RTNE fp32 -> bf16
  uint32_t u = __float_as_uint(f);
  u += 0x7FFFu + ((u >> 16) & 1u);
  return (uint16_t)(u >> 16);
}
__device__ __forceinline__ short8 pack8(float4 a, float4 b) {
  short8 r;
  r[0] = (short)f2b(a.x); r[1] = (short)f2b(a.y);
  r[2] = (short)f2b(a.z); r[3] = (short)f2b(a.w);
  r[4] = (short)f2b(b.x); r[5] = (short)f2b(b.y);
  r[6] = (short)f2b(b.z); r[7] = (short)f2b(b.w);
  return r;
}

__global__ __launch_bounds__(256, 2)
void swa_mfma(const float* __restrict__ Q, const float* __restrict__ K,
              const float* __restrict__ V, float* __restrict__ O) {
  // 33 KB LDS total (was 53 KB): Ssc fp32 score buffer is gone.
  __shared__ __align__(16) uint16_t Vt[64 * PVT];   // V^T: Vt[d][kpos] bf16
  __shared__ __align__(16) uint16_t Pw[TQ * PP];    // unnormalized P' bf16
  __shared__ __align__(16) float    Pp[2][16][4];   // [qt][q][{m0,S0,m1,S1}]

  const int tile = blockIdx.x;           // 0..63
  const int h    = blockIdx.y;           // 0..7
  const int tid  = threadIdx.x;
  const int g0   = tile * TQ - 64;       // global kpos of local col 0

  // ---------- stage V^T into LDS (clamp rows; masked by P'=0 later) ----------
#pragma unroll
  for (int it = 0; it < 10; ++it) {
    int task = tid + it * 256;           // 2560 tasks: 64 d x 40 col-quads
    int d    = task & 63;
    int cq   = task >> 6;                // 0..39
    int gb   = g0 + (cq << 2);
    float v[4];
#pragma unroll
    for (int k = 0; k < 4; ++k) {
      int g = gb + k;
      g = g < 0 ? 0 : (g > S_LEN - 1 ? S_LEN - 1 : g);
      v[k] = V[((g * NH + h) << 6) + d];           // coalesced along d
    }
    uint32_t p01 = (uint32_t)f2b(v[0]) | ((uint32_t)f2b(v[1]) << 16);
    uint32_t p23 = (uint32_t)f2b(v[2]) | ((uint32_t)f2b(v[3]) << 16);
    uint32_t* dst = (uint32_t*)&Vt[d * PVT + (cq << 2)];
    dst[0] = p01; dst[1] = p23;
  }
  // NOTE: no barrier here — Vt is first read only after the single barrier below.

  const int lane = tid & 63;
  const int w    = tid >> 6;
  const int r16  = lane & 15;
  const int quad = lane >> 4;
  const int qt   = w & 1;                // wave's 16-query tile (0/1)
  const int half = w >> 1;               // wave's k-window half (0: k 0..95, 1: k 96..159)
  const int NT   = half ? 4 : 6;         // 16-wide k-tiles owned (96/64 split, kt32-aligned)
  const int kt0  = half ? 6 : 0;

  // ---------- Q as the B-operand: lane r16 = query col, k-chunk = d ----------
  const int qrow = tile * TQ + qt * 16 + r16;
  const float* qb = Q + ((qrow * NH + h) << 6) + (quad << 3);
  float4 q0 = *(const float4*)(qb);
  float4 q1 = *(const float4*)(qb + 4);
  float4 q2 = *(const float4*)(qb + 32);
  float4 q3 = *(const float4*)(qb + 36);
  const float sc = 0.125f;               // 1/sqrt(64)
  q0.x*=sc;q0.y*=sc;q0.z*=sc;q0.w*=sc;  q1.x*=sc;q1.y*=sc;q1.z*=sc;q1.w*=sc;
  q2.x*=sc;q2.y*=sc;q2.z*=sc;q2.w*=sc;  q3.x*=sc;q3.y*=sc;q3.z*=sc;q3.w*=sc;
  short8 bq0 = pack8(q0, q1);            // d = quad*8 .. +7
  short8 bq1 = pack8(q2, q3);            // d = 32+quad*8 .. +7

  // ---------- swapped QK^T: acc[u][reg] = S[kpos=(kt0+u)*16+quad*4+reg][q=r16] ----------
  floatx4 acc[6];
#pragma unroll
  for (int u = 0; u < 6; ++u) acc[u] = (floatx4){0.f, 0.f, 0.f, 0.f};

#pragma unroll
  for (int u = 0; u < 6; ++u) if (u < NT) {
    int g = g0 + (kt0 + u) * 16 + r16;   // K row for A-frag (lane r16 = kpos row)
    g = g < 0 ? 0 : (g > S_LEN - 1 ? S_LEN - 1 : g);   // clamp: finite garbage, masked below
    const float* kb = K + ((g * NH + h) << 6) + (quad << 3);
    float4 k0 = *(const float4*)(kb);
    float4 k1 = *(const float4*)(kb + 4);
    float4 k2 = *(const float4*)(kb + 32);
    float4 k3 = *(const float4*)(kb + 36);
    short8 ak0 = pack8(k0, k1);
    short8 ak1 = pack8(k2, k3);
    acc[u] = __builtin_amdgcn_mfma_f32_16x16x32_bf16(ak0, bq0, acc[u], 0, 0, 0);
    acc[u] = __builtin_amdgcn_mfma_f32_16x16x32_bf16(ak1, bq1, acc[u], 0, 0, 0);
  }

  // ---------- in-register softmax: mask, 2-shfl cross-quad max/sum ----------
  float mx = -INFINITY;
#pragma unroll
  for (int u = 0; u < 6; ++u) if (u < NT) {
#pragma unroll
    for (int r = 0; r < 4; ++r) {
      int kpos = (kt0 + u) * 16 + (quad << 2) + r;
      int g    = g0 + kpos;
      bool ok  = (g >= 0) && (g < S_LEN) && (g >= qrow - 64) && (g <= qrow + 64);
      float s  = ok ? acc[u][r] : -INFINITY;
      acc[u][r] = s;
      mx = fmaxf(mx, s);
    }
  }
  mx = fmaxf(mx, __shfl_xor(mx, 16, 64));   // reduce over the 4 quads (same q)
  mx = fmaxf(mx, __shfl_xor(mx, 32, 64));
  mx = fmaxf(mx, -3.0e38f);                 // empty-half guard: keeps exp() NaN-free

  float sum = 0.f;
  uint32_t* prow = (uint32_t*)&Pw[(qt * 16 + r16) * PP];
#pragma unroll
  for (int u = 0; u < 6; ++u) if (u < NT) {
    float e0 = __expf(acc[u][0] - mx);      // -inf -> 0 automatically
    float e1 = __expf(acc[u][1] - mx);
    float e2 = __expf(acc[u][2] - mx);
    float e3 = __expf(acc[u][3] - mx);
    sum += (e0 + e1) + (e2 + e3);
    uint32x2 pw;
    pw[0] = (uint32_t)f2b(e0) | ((uint32_t)f2b(e1) << 16);
    pw[1] = (uint32_t)f2b(e2) | ((uint32_t)f2b(e3) << 16);
    int ci = (kt0 + u) * 16 + (quad << 2);  // unnormalized P' -> LDS, b64 write
    *(uint32x2*)&prow[ci >> 1] = pw;
  }
  sum += __shfl_xor(sum, 16, 64);
  sum += __shfl_xor(sum, 32, 64);
  if (quad == 0) {                          // per-query partials for the merge
    Pp[qt][r16][half * 2]     = mx;
    Pp[qt][r16][half * 2 + 1] = sum;
  }

  __syncthreads();                          // the ONLY barrier

  // ---------- PV: two k-group accumulators, flash-style merge epilogue ----------
  short8 pa[5];
  const uint16_t* Pr = &Pw[(qt * 16 + r16) * PP + (quad << 3)];
#pragma unroll
  for (int kt = 0; kt < 5; ++kt)
    pa[kt] = *(const short8*)(Pr + kt * 32);     // A-frag: P'[q][k]

  float ca[4], cb[4];                            // per-output-row merge factors
#pragma unroll
  for (int r = 0; r < 4; ++r) {
    float4 p = *(const float4*)(&Pp[qt][(quad << 2) + r][0]);  // broadcast read
    float m  = fmaxf(p.x, p.z);
    float f0 = __expf(p.x - m);
    float f1 = __expf(p.z - m);
    float rs = 1.0f / (f0 * p.y + f1 * p.w);
    ca[r] = f0 * rs;
    cb[r] = f1 * rs;
  }

#pragma unroll
  for (int t = 0; t < 2; ++t) {
    int dt = half * 2 + t;                       // this wave's d-tiles
    const uint16_t* Vr = &Vt[(dt * 16 + r16) * PVT + (quad << 3)];
    floatx4 oA = {0.f, 0.f, 0.f, 0.f};           // k 0..95   (half0's basis m0)
    floatx4 oB = {0.f, 0.f, 0.f, 0.f};           // k 96..159 (half1's basis m1)
#pragma unroll
    for (int kt = 0; kt < 3; ++kt)
      oA = __builtin_amdgcn_mfma_f32_16x16x32_bf16(pa[kt], *(const short8*)(Vr + kt * 32), oA, 0, 0, 0);
#pragma unroll
    for (int kt = 3; kt < 5; ++kt)
      oB = __builtin_amdgcn_mfma_f32_16x16x32_bf16(pa[kt], *(const short8*)(Vr + kt * 32), oB, 0, 0, 0);
    int orow = tile * TQ + qt * 16 + (quad << 2);
    int d    = dt * 16 + r16;
#pragma unroll
    for (int r = 0; r < 4; ++r)
      O[(((orow + r) * NH + h) << 6) + d] = ca[r] * oA[r] + cb[r] * oB[r];
  }
}

extern "C" void kernel_launch(void* const* d_in, const int* in_sizes, int n_in,
                              void* d_out, int out_size, void* d_ws, size_t ws_size,
                              hipStream_t stream) {
  const float* Q = (const float*)d_in[0];
  const float* K = (const float*)d_in[1];
  const float* V = (const float*)d_in[2];
  float* O = (float*)d_out;
  dim3 grid(S_LEN / TQ, NH);
  swa_mfma<<<grid, 256, 0, stream>>>(Q, K, V, O);
}

// Round 10
// 75.366 us; speedup vs baseline: 1.0313x; 1.0024x over previous
//
#include <hip/hip_runtime.h>
#include <stdint.h>

#define S_LEN 2048
#define NH    8
#define TQ    32            // queries per block
#define PVT   168           // Vt LDS stride (bf16): 336 B rows, b128-aligned
#define PP    168           // P  LDS stride (bf16), same property

typedef __attribute__((ext_vector_type(8))) short  short8;   // 8 bf16 (4 VGPRs)
typedef __attribute__((ext_vector_type(4))) float  floatx4;  // MFMA C/D
typedef __attribute__((ext_vector_type(2))) unsigned int uint32x2;

__device__ __forceinline__ uint16_t f2b(float f) {           // RTNE fp32 -> bf16
  uint32_t u = __float_as_uint(f);
  u += 0x7FFFu + ((u >> 16) & 1u);
  return (uint16_t)(u >> 16);
}
__device__ __forceinline__ short8 pack8(float4 a, float4 b) {
  short8 r;
  r[0] = (short)f2b(a.x); r[1] = (short)f2b(a.y);
  r[2] = (short)f2b(a.z); r[3] = (short)f2b(a.w);
  r[4] = (short)f2b(b.x); r[5] = (short)f2b(b.y);
  r[6] = (short)f2b(b.z); r[7] = (short)f2b(b.w);
  return r;
}

// 512 threads = 8 waves/block; 512 blocks -> 2 blocks/CU -> 16 waves/CU = 4/SIMD
// (was 2/SIMD). Second launch_bounds arg = 4 waves/EU -> VGPR cap 128.
__global__ __launch_bounds__(512, 4)
void swa_mfma(const float* __restrict__ Q, const float* __restrict__ K,
              const float* __restrict__ V, float* __restrict__ O) {
  __shared__ __align__(16) uint16_t Vt[64 * PVT];   // V^T: Vt[d][kpos] bf16  21,504 B
  __shared__ __align__(16) uint16_t Pw[TQ * PP];    // unnormalized P' bf16   10,752 B
  __shared__ __align__(16) float    Pp[2][16][8];   // [qt][q][{m,S} x 4 kq]   1,024 B

  const int tile = blockIdx.x;           // 0..63
  const int h    = blockIdx.y;           // 0..7
  const int tid  = threadIdx.x;
  const int g0   = tile * TQ - 64;       // global kpos of local col 0

  // ---------- stage V^T into LDS (clamp rows; masked by P'=0 later) ----------
#pragma unroll
  for (int it = 0; it < 5; ++it) {
    int task = tid + it * 512;           // 2560 tasks: 64 d x 40 col-quads
    int d    = task & 63;
    int cq   = task >> 6;                // 0..39
    int gb   = g0 + (cq << 2);
    float v[4];
#pragma unroll
    for (int k = 0; k < 4; ++k) {
      int g = gb + k;
      g = g < 0 ? 0 : (g > S_LEN - 1 ? S_LEN - 1 : g);
      v[k] = V[((g * NH + h) << 6) + d];           // coalesced along d
    }
    uint32_t p01 = (uint32_t)f2b(v[0]) | ((uint32_t)f2b(v[1]) << 16);
    uint32_t p23 = (uint32_t)f2b(v[2]) | ((uint32_t)f2b(v[3]) << 16);
    uint32_t* dst = (uint32_t*)&Vt[d * PVT + (cq << 2)];
    dst[0] = p01; dst[1] = p23;
  }
  // NOTE: no barrier here — Vt is first read only after the single barrier below.

  const int lane = tid & 63;
  const int w    = tid >> 6;             // 0..7
  const int r16  = lane & 15;
  const int quad = lane >> 4;
  const int qt   = w & 1;                // wave's 16-query tile (0/1)
  const int kq   = w >> 1;               // wave's k-quarter (0..3)
  const int NT   = (kq == 0) ? 4 : 2;    // 16-wide k-tiles owned: {4,2,2,2} (32-aligned)
  const int kt0  = (kq == 0) ? 0 : 2 + 2 * kq;   // first tile: {0,4,6,8}

  // ---------- Q as the B-operand: lane r16 = query col, k-chunk = d ----------
  const int qrow = tile * TQ + qt * 16 + r16;
  const float* qb = Q + ((qrow * NH + h) << 6) + (quad << 3);
  float4 q0 = *(const float4*)(qb);
  float4 q1 = *(const float4*)(qb + 4);
  float4 q2 = *(const float4*)(qb + 32);
  float4 q3 = *(const float4*)(qb + 36);
  const float sc = 0.125f;               // 1/sqrt(64)
  q0.x*=sc;q0.y*=sc;q0.z*=sc;q0.w*=sc;  q1.x*=sc;q1.y*=sc;q1.z*=sc;q1.w*=sc;
  q2.x*=sc;q2.y*=sc;q2.z*=sc;q2.w*=sc;  q3.x*=sc;q3.y*=sc;q3.z*=sc;q3.w*=sc;
  short8 bq0 = pack8(q0, q1);            // d = quad*8 .. +7
  short8 bq1 = pack8(q2, q3);            // d = 32+quad*8 .. +7

  // ---------- swapped QK^T: acc[u][rg] = S[kpos=(kt0+u)*16+quad*4+rg][q=r16] ----------
  floatx4 acc[4];
#pragma unroll
  for (int u = 0; u < 4; ++u) acc[u] = (floatx4){0.f, 0.f, 0.f, 0.f};

#pragma unroll
  for (int u = 0; u < 4; ++u) if (u < NT) {
    int g = g0 + (kt0 + u) * 16 + r16;   // K row for A-frag (lane r16 = kpos row)
    g = g < 0 ? 0 : (g > S_LEN - 1 ? S_LEN - 1 : g);   // clamp: finite garbage, masked below
    const float* kb = K + ((g * NH + h) << 6) + (quad << 3);
    float4 k0 = *(const float4*)(kb);
    float4 k1 = *(const float4*)(kb + 4);
    float4 k2 = *(const float4*)(kb + 32);
    float4 k3 = *(const float4*)(kb + 36);
    short8 ak0 = pack8(k0, k1);
    short8 ak1 = pack8(k2, k3);
    acc[u] = __builtin_amdgcn_mfma_f32_16x16x32_bf16(ak0, bq0, acc[u], 0, 0, 0);
    acc[u] = __builtin_amdgcn_mfma_f32_16x16x32_bf16(ak1, bq1, acc[u], 0, 0, 0);
  }

  // ---------- in-register softmax (per k-quarter): mask, 2-shfl cross-quad max/sum ----------
  float mx = -INFINITY;
#pragma unroll
  for (int u = 0; u < 4; ++u) if (u < NT) {
#pragma unroll
    for (int rg = 0; rg < 4; ++rg) {
      int kpos = (kt0 + u) * 16 + (quad << 2) + rg;
      int g    = g0 + kpos;
      bool ok  = (g >= 0) && (g < S_LEN) && (g >= qrow - 64) && (g <= qrow + 64);
      float s  = ok ? acc[u][rg] : -INFINITY;
      acc[u][rg] = s;
      mx = fmaxf(mx, s);
    }
  }
  mx = fmaxf(mx, __shfl_xor(mx, 16, 64));   // reduce over the 4 quads (same q)
  mx = fmaxf(mx, __shfl_xor(mx, 32, 64));
  mx = fmaxf(mx, -3.0e38f);                 // empty-quarter guard: keeps exp() NaN-free

  float sum = 0.f;
  uint32_t* prow = (uint32_t*)&Pw[(qt * 16 + r16) * PP];
#pragma unroll
  for (int u = 0; u < 4; ++u) if (u < NT) {
    float e0 = __expf(acc[u][0] - mx);      // -inf -> 0 automatically
    float e1 = __expf(acc[u][1] - mx);
    float e2 = __expf(acc[u][2] - mx);
    float e3 = __expf(acc[u][3] - mx);
    sum += (e0 + e1) + (e2 + e3);
    uint32x2 pw;
    pw[0] = (uint32_t)f2b(e0) | ((uint32_t)f2b(e1) << 16);
    pw[1] = (uint32_t)f2b(e2) | ((uint32_t)f2b(e3) << 16);
    int ci = (kt0 + u) * 16 + (quad << 2);  // unnormalized P' -> LDS, b64 write
    *(uint32x2*)&prow[ci >> 1] = pw;
  }
  sum += __shfl_xor(sum, 16, 64);
  sum += __shfl_xor(sum, 32, 64);
  if (quad == 0) {                          // per-(query, k-quarter) partials
    Pp[qt][r16][kq * 2]     = mx;
    Pp[qt][r16][kq * 2 + 1] = sum;
  }

  __syncthreads();                          // the ONLY barrier

  // ---------- PV: 4 basis accumulators, exact 4-way flash merge epilogue ----------
  short8 pa[5];
  const uint16_t* Pr = &Pw[(qt * 16 + r16) * PP + (quad << 3)];
#pragma unroll
  for (int ks = 0; ks < 5; ++ks)
    pa[ks] = *(const short8*)(Pr + ks * 32);     // A-frag: P'[q][k]

  const int dq = kq;                             // this wave's 16-wide d-tile
  const uint16_t* Vr = &Vt[(dq * 16 + r16) * PVT + (quad << 3)];
  floatx4 o0 = {0.f,0.f,0.f,0.f};                // basis kq0: k-steps 0,1 (tiles 0-3)
  floatx4 o1 = {0.f,0.f,0.f,0.f};                // basis kq1: k-step 2   (tiles 4-5)
  floatx4 o2 = {0.f,0.f,0.f,0.f};                // basis kq2: k-step 3   (tiles 6-7)
  floatx4 o3 = {0.f,0.f,0.f,0.f};                // basis kq3: k-step 4   (tiles 8-9)
  o0 = __builtin_amdgcn_mfma_f32_16x16x32_bf16(pa[0], *(const short8*)(Vr +   0), o0, 0, 0, 0);
  o0 = __builtin_amdgcn_mfma_f32_16x16x32_bf16(pa[1], *(const short8*)(Vr +  32), o0, 0, 0, 0);
  o1 = __builtin_amdgcn_mfma_f32_16x16x32_bf16(pa[2], *(const short8*)(Vr +  64), o1, 0, 0, 0);
  o2 = __builtin_amdgcn_mfma_f32_16x16x32_bf16(pa[3], *(const short8*)(Vr +  96), o2, 0, 0, 0);
  o3 = __builtin_amdgcn_mfma_f32_16x16x32_bf16(pa[4], *(const short8*)(Vr + 128), o3, 0, 0, 0);

  float c0[4], c1[4], c2[4], c3[4];              // per-output-row merge factors
#pragma unroll
  for (int rg = 0; rg < 4; ++rg) {
    const float* pp = &Pp[qt][(quad << 2) + rg][0];      // row = output row (quad*4+rg)
    float4 pA = *(const float4*)(pp);                    // {m0,S0,m1,S1}
    float4 pB = *(const float4*)(pp + 4);                // {m2,S2,m3,S3}
    float m  = fmaxf(fmaxf(pA.x, pA.z), fmaxf(pB.x, pB.z));
    float f0 = __expf(pA.x - m);
    float f1 = __expf(pA.z - m);
    float f2 = __expf(pB.x - m);
    float f3 = __expf(pB.z - m);
    float rs = 1.0f / (f0 * pA.y + f1 * pA.w + f2 * pB.y + f3 * pB.w);
    c0[rg] = f0 * rs; c1[rg] = f1 * rs; c2[rg] = f2 * rs; c3[rg] = f3 * rs;
  }

  const int orow = tile * TQ + qt * 16 + (quad << 2);
  const int d    = dq * 16 + r16;
#pragma unroll
  for (int rg = 0; rg < 4; ++rg)
    O[(((orow + rg) * NH + h) << 6) + d] =
        c0[rg] * o0[rg] + c1[rg] * o1[rg] + c2[rg] * o2[rg] + c3[rg] * o3[rg];
}

extern "C" void kernel_launch(void* const* d_in, const int* in_sizes, int n_in,
                              void* d_out, int out_size, void* d_ws, size_t ws_size,
                              hipStream_t stream) {
  const float* Q = (const float*)d_in[0];
  const float* K = (const float*)d_in[1];
  const float* V = (const float*)d_in[2];
  float* O = (float*)d_out;
  dim3 grid(S_LEN / TQ, NH);
  swa_mfma<<<grid, 512, 0, stream>>>(Q, K, V, O);
}